// Round 1
// baseline (115.795 us; speedup 1.0000x reference)
//
#include <hip/hip_runtime.h>

// Input indices (setup_inputs() dict order):
//  0:x 1:W1 2:b1 3:gn1_g 4:gn1_b 5:W2 6:b2 7:W3 8:b3 9:gn2_g 10:gn2_b
//  11:fc1_W[16384,512] 12:fc1_b[512] 13:fc2_W[512,128] 14:fc2_b[128]
//  15:wc_W[128] 16:wc_b[1] 17:sel_W[128] 18:sel_b[1]
//
// Math note (verified in prior session): groups==C in both GroupNorms ->
// per-group var==0 exactly -> GN output == beta. The whole conv front-end is
// dead; flat[k] = relu(gn2_b[k>>8]) for every batch row, so
//   y1 = relu( sum_c relu(gn2_b[c]) * colsum_c(fc1_W) + fc1_b )
// and the two heads are two scalars replicated 128x.
//
// Key consequence exploited here: channels with gn2_b[c] <= 0 contribute
// EXACTLY zero -> their 256-row slab of fc1_W need not be read (expected ~half
// of the 32 MiB).

// ---------------- Stage 1: weighted column-sum of fc1_W ----------------
// Grid: 512 blocks x 256 threads. Block b: rb = b>>2 (row-block, 128 rows,
// channel rb>>1), q = b&3 (column quarter, 128 cols). (q in the LOW bits so
// the two blocks landing on the same CU get different channels -> dead-channel
// early exits stay load-balanced.)
// Each block writes its disjoint 128-float slice of parts[128][512]. No atomics.
__global__ __launch_bounds__(256) void fc1_partial_kernel(
    const float* __restrict__ fc1_W,   // [16384, 512] row-major
    const float* __restrict__ gn2_b,   // [64]
    float* __restrict__ parts)         // [128][512] floats (256 KB)
{
    const int b  = blockIdx.x;
    const int rb = b >> 2;             // 0..127, rows rb*128 .. +127
    const int q  = b & 3;              // column quarter
    const int t  = threadIdx.x;
    const int cg = t & 31;             // float4 col-group within quarter
    const int rs = t >> 5;             // row-slot 0..7 (16 rows each)

    float vc = gn2_b[rb >> 1];         // channel = (rb*128)>>8 = rb>>1
    vc = vc > 0.0f ? vc : 0.0f;

    float4* __restrict__ parts4 = reinterpret_cast<float4*>(parts);
    const int out_idx = rb * 128 + q * 32;   // float4 index of block's slice

    if (vc == 0.0f) {                  // dead channel: slab contributes 0
        if (t < 32) parts4[out_idx + t] = float4{0.f, 0.f, 0.f, 0.f};
        return;                        // block-uniform branch
    }

    const int col0 = q * 128 + cg * 4;
    const float4* __restrict__ p = reinterpret_cast<const float4*>(
        fc1_W + (size_t)(rb * 128 + rs * 16) * 512 + col0);

    float4 a = float4{0.f, 0.f, 0.f, 0.f};
#pragma unroll
    for (int r = 0; r < 16; ++r) {     // float4 row stride = 512/4 = 128
        float4 v = p[(size_t)r * 128];
        a.x += v.x; a.y += v.y; a.z += v.z; a.w += v.w;
    }

    __shared__ float4 lds4[256];
    lds4[t] = a;
    __syncthreads();
    if (t < 32) {
        float4 s = lds4[t];
#pragma unroll
        for (int ss = 1; ss < 8; ++ss) {
            float4 v = lds4[ss * 32 + t];
            s.x += v.x; s.y += v.y; s.z += v.z; s.w += v.w;
        }
        s.x *= vc; s.y *= vc; s.z *= vc; s.w *= vc;
        parts4[out_idx + t] = s;
    }
}

// ---------------- Stage 2: tail (1 block x 512 threads) ----------------
__global__ __launch_bounds__(512) void tail_kernel(
    const float* __restrict__ parts,   // [128][512]
    const float* __restrict__ fc1_b,   // [512]
    const float* __restrict__ fc2_W,   // [512,128] row-major
    const float* __restrict__ fc2_b,   // [128]
    const float* __restrict__ wc_W,    // [128]
    const float* __restrict__ wc_b,    // [1]
    const float* __restrict__ sel_W,   // [128]
    const float* __restrict__ sel_b,   // [1]
    float* __restrict__ out)           // [256]: wc[128] then sel[128]
{
    __shared__ float4 red4[512];       // 8 KB, reused across phases
    __shared__ float  y1s[512];
    __shared__ float  scal[2];
    const int t = threadIdx.x;

    // Phase 1: y1 = relu(colsum(parts) + fc1_b)
    {
        const float4* __restrict__ p4 = reinterpret_cast<const float4*>(parts);
        const int cg = t & 127;        // float4 column group 0..127
        const int rg = t >> 7;         // row quarter: 32 partial-rows each
        float4 a = float4{0.f, 0.f, 0.f, 0.f};
#pragma unroll 8
        for (int r = 0; r < 32; ++r) {
            float4 v = p4[(size_t)(rg * 32 + r) * 128 + cg];
            a.x += v.x; a.y += v.y; a.z += v.z; a.w += v.w;
        }
        red4[t] = a;
    }
    __syncthreads();
    if (t < 128) {
        float4 a = red4[t];
        float4 b1 = red4[128 + t], c1 = red4[256 + t], d1 = red4[384 + t];
        a.x += b1.x + c1.x + d1.x;  a.y += b1.y + c1.y + d1.y;
        a.z += b1.z + c1.z + d1.z;  a.w += b1.w + c1.w + d1.w;
        float4 fb = reinterpret_cast<const float4*>(fc1_b)[t];
        y1s[4 * t + 0] = fmaxf(a.x + fb.x, 0.f);
        y1s[4 * t + 1] = fmaxf(a.y + fb.y, 0.f);
        y1s[4 * t + 2] = fmaxf(a.z + fb.z, 0.f);
        y1s[4 * t + 3] = fmaxf(a.w + fb.w, 0.f);
    }
    __syncthreads();

    // Phase 2: y2 = relu(y1 @ fc2_W + fc2_b), float4 over columns.
    // thread: cg = t&31 -> cols 4cg..4cg+3 ; ig = t>>5 -> i in [ig*32, ig*32+32)
    {
        const float4* __restrict__ w4 = reinterpret_cast<const float4*>(fc2_W);
        const int cg = t & 31;
        const int ig = t >> 5;
        float4 a = float4{0.f, 0.f, 0.f, 0.f};
#pragma unroll 8
        for (int k = 0; k < 32; ++k) {
            const int i = ig * 32 + k;
            const float y = y1s[i];
            float4 w = w4[(size_t)i * 32 + cg];
            a.x += y * w.x; a.y += y * w.y; a.z += y * w.z; a.w += y * w.w;
        }
        red4[ig * 32 + cg] = a;
    }
    __syncthreads();

    // Phase 3: reduce 16 i-groups, bias+relu, both heads via shuffle reduce.
    if (t < 32) {
        float4 a = float4{0.f, 0.f, 0.f, 0.f};
#pragma unroll
        for (int ig = 0; ig < 16; ++ig) {
            float4 v = red4[ig * 32 + t];
            a.x += v.x; a.y += v.y; a.z += v.z; a.w += v.w;
        }
        float4 fb = reinterpret_cast<const float4*>(fc2_b)[t];
        a.x = fmaxf(a.x + fb.x, 0.f);
        a.y = fmaxf(a.y + fb.y, 0.f);
        a.z = fmaxf(a.z + fb.z, 0.f);
        a.w = fmaxf(a.w + fb.w, 0.f);
        float4 wv = reinterpret_cast<const float4*>(wc_W)[t];
        float4 sv = reinterpret_cast<const float4*>(sel_W)[t];
        float s0 = a.x * wv.x + a.y * wv.y + a.z * wv.z + a.w * wv.w;
        float s1 = a.x * sv.x + a.y * sv.y + a.z * sv.z + a.w * sv.w;
#pragma unroll
        for (int off = 16; off >= 1; off >>= 1) {   // lanes 0..31, xor stays in-range
            s0 += __shfl_xor(s0, off);
            s1 += __shfl_xor(s1, off);
        }
        if (t == 0) { scal[0] = s0 + wc_b[0]; scal[1] = s1 + sel_b[0]; }
    }
    __syncthreads();

    if (t < 128) {
        out[t]       = scal[0];   // wc head, replicated over batch
        out[128 + t] = scal[1];   // sel head, replicated over batch
    }
}

// ---------------- Fallback path (previous harness-verified kernels) ----------
// Used only if ws_size < 256 KB. Needs 2 KB of ws + a memset dispatch.
#define ROWS_PER_BLOCK 64

__global__ __launch_bounds__(512) void fc1_reduce_kernel_atomic(
    const float* __restrict__ fc1_W,
    const float* __restrict__ gn2_b,
    float* __restrict__ y1acc)
{
    const int j   = threadIdx.x;
    const int bid = blockIdx.x;
    const int row0 = bid * ROWS_PER_BLOCK;
    float vc = gn2_b[bid >> 2];
    vc = vc > 0.0f ? vc : 0.0f;
    const float* p = fc1_W + (size_t)row0 * 512 + j;
    float acc = 0.0f;
#pragma unroll
    for (int r = 0; r < ROWS_PER_BLOCK; ++r) acc += p[(size_t)r * 512];
    atomicAdd(&y1acc[j], vc * acc);
}

__global__ __launch_bounds__(512) void tail_kernel_old(
    const float* __restrict__ y1acc,
    const float* __restrict__ fc1_b,
    const float* __restrict__ fc2_W,
    const float* __restrict__ fc2_b,
    const float* __restrict__ wc_W,
    const float* __restrict__ wc_b,
    const float* __restrict__ sel_W,
    const float* __restrict__ sel_b,
    float* __restrict__ out)
{
    __shared__ float y1sh[512];
    __shared__ float part[512];
    __shared__ float redwc[128];
    __shared__ float redsel[128];
    __shared__ float scal[2];
    const int t = threadIdx.x;
    float y1 = y1acc[t] + fc1_b[t];
    y1sh[t] = y1 > 0.0f ? y1 : 0.0f;
    __syncthreads();
    const int j = t & 127;
    const int q = t >> 7;
    float acc = 0.0f;
    const int i0 = q * 128;
#pragma unroll 8
    for (int i = 0; i < 128; ++i)
        acc += y1sh[i0 + i] * fc2_W[(size_t)(i0 + i) * 128 + j];
    part[t] = acc;
    __syncthreads();
    if (t < 128) {
        float y2 = part[t] + part[128 + t] + part[256 + t] + part[384 + t] + fc2_b[t];
        y2 = y2 > 0.0f ? y2 : 0.0f;
        redwc[t]  = y2 * wc_W[t];
        redsel[t] = y2 * sel_W[t];
    }
    __syncthreads();
    if (t == 0) {
        float s0 = 0.0f, s1 = 0.0f;
        for (int i = 0; i < 128; ++i) { s0 += redwc[i]; s1 += redsel[i]; }
        scal[0] = s0 + wc_b[0];
        scal[1] = s1 + sel_b[0];
    }
    __syncthreads();
    if (t < 128) {
        out[t]       = scal[0];
        out[128 + t] = scal[1];
    }
}

extern "C" void kernel_launch(void* const* d_in, const int* in_sizes, int n_in,
                              void* d_out, int out_size, void* d_ws, size_t ws_size,
                              hipStream_t stream) {
    (void)in_sizes; (void)n_in; (void)out_size;

    const float* gn2_b = (const float*)d_in[10];
    const float* fc1_W = (const float*)d_in[11];
    const float* fc1_b = (const float*)d_in[12];
    const float* fc2_W = (const float*)d_in[13];
    const float* fc2_b = (const float*)d_in[14];
    const float* wc_W  = (const float*)d_in[15];
    const float* wc_b  = (const float*)d_in[16];
    const float* sel_W = (const float*)d_in[17];
    const float* sel_b = (const float*)d_in[18];

    float* out = (float*)d_out;

    const size_t need = (size_t)128 * 512 * sizeof(float);  // 256 KB partials
    if (ws_size >= need) {
        float* parts = (float*)d_ws;   // fully overwritten; poison is harmless
        fc1_partial_kernel<<<512, 256, 0, stream>>>(fc1_W, gn2_b, parts);
        tail_kernel<<<1, 512, 0, stream>>>(parts, fc1_b, fc2_W, fc2_b,
                                           wc_W, wc_b, sel_W, sel_b, out);
    } else {
        // previous harness-verified path (2 KB ws)
        float* y1acc = (float*)d_ws;
        hipMemsetAsync(y1acc, 0, 512 * sizeof(float), stream);
        fc1_reduce_kernel_atomic<<<256, 512, 0, stream>>>(fc1_W, gn2_b, y1acc);
        tail_kernel_old<<<1, 512, 0, stream>>>(y1acc, fc1_b, fc2_W, fc2_b,
                                               wc_W, wc_b, sel_W, sel_b, out);
    }
}